// Round 5
// baseline (487.571 us; speedup 1.0000x reference)
//
#include <hip/hip_runtime.h>

#define D 128          // D_IN == D_OUT == 128
#define NREL 4
#define BINSHIFT 8     // 256 buckets per coarse bin
#define NBK 256        // buckets per bin
#define BCAP 1664      // edge capacity per bin window (mean 1280, +10.7 sigma)

typedef __attribute__((ext_vector_type(8))) short short8;
typedef __attribute__((ext_vector_type(4))) float f32x4;

static __device__ inline unsigned short f2bf(float f) {
    unsigned int u = __float_as_uint(f);
    u += 0x7fffu + ((u >> 16) & 1u);   // round-to-nearest-even
    return (unsigned short)(u >> 16);
}

// ---------------------------------------------------------------------------
// part1 + prep, scatter edition. Bucket key DST-MAJOR: g = dst*4 + rel, so
// one bin (256 buckets) = 64 dsts x 4 rels = one M=64, K=512 output tile.
//  A) grid-stride DIRECT scatter: pos = atomicAdd(binCnt[bin]), write entry
//     to part[bin*BCAP+pos]. No LDS, no barriers — agg_gemm re-sorts each
//     bin anyway, so window order is irrelevant. Scattered 4B writes stay
//     L2-resident (10.4 MB region, light competing streams).
//  B) grid-stride xcast (f32->bf16), W swizzle, bias sum.
// Entry = src | (g&255)<<17, bin = g>>8. LDS = 0 -> occupancy-unbound.
// ---------------------------------------------------------------------------
__global__ __launch_bounds__(256) void part1prep_kernel(
    const float* __restrict__ x,      // [N][128]
    const float* __restrict__ W,      // [4][128][128]
    const float* __restrict__ bias,   // [4][128]
    const int* __restrict__ src, const int* __restrict__ dst,
    int* __restrict__ binCnt, unsigned int* __restrict__ part,
    unsigned short* __restrict__ xB,  // [N][128] bf16
    unsigned short* __restrict__ Wsw, // [16][8][64][8] bf16
    float* __restrict__ bsum,         // [128]
    int E, int N, int nbins, int total)
{
    const int t     = threadIdx.x;
    const int gtid  = blockIdx.x * 256 + t;
    const int gsize = gridDim.x * 256;
    const int E2 = 2 * E, E3 = 3 * E;

    // ---- A: direct scatter, 4 edges/thread via int4 loads ----
    const int nq = total >> 2;
    for (int i = gtid; i < nq; i += gsize) {
        const int e = i * 4;
        const int4 s4 = ((const int4*)src)[i];
        const int4 d4 = ((const int4*)dst)[i];
        #pragma unroll
        for (int k = 0; k < 4; ++k) {
            const int ek = e + k;
            const int sk = (k == 0) ? s4.x : (k == 1) ? s4.y : (k == 2) ? s4.z : s4.w;
            const int dk = (k == 0) ? d4.x : (k == 1) ? d4.y : (k == 2) ? d4.z : d4.w;
            const int r  = (ek >= E) + (ek >= E2) + (ek >= E3);
            const int g  = (dk << 2) | r;               // DST-MAJOR key
            const unsigned entry = (unsigned)sk | ((unsigned)(g & (NBK - 1)) << 17);
            const int bin = g >> BINSHIFT;
            const int pos = atomicAdd(&binCnt[bin], 1);
            if (pos < BCAP)                             // 10.7-sigma guard
                part[(size_t)bin * BCAP + pos] = entry;
        }
    }
    for (int e = (nq << 2) + gtid; e < total; e += gsize) {   // tail (total%4)
        const int r  = (e >= E) + (e >= E2) + (e >= E3);
        const int g  = (dst[e] << 2) | r;
        const unsigned entry = (unsigned)src[e] | ((unsigned)(g & (NBK - 1)) << 17);
        const int bin = g >> BINSHIFT;
        const int pos = atomicAdd(&binCnt[bin], 1);
        if (pos < BCAP)
            part[(size_t)bin * BCAP + pos] = entry;
    }

    // ---- B: prep (grid-stride) ----
    if (gtid < D)
        bsum[gtid] = bias[gtid] + bias[D + gtid] + bias[2 * D + gtid] + bias[3 * D + gtid];

    for (int gid = gtid; gid < 8192; gid += gsize) {
        const int l   = gid & 63;
        const int ct  = (gid >> 6) & 7;
        const int kb  = gid >> 9;
        const int rel = kb >> 2;
        const int kbase = (kb & 3) * 32 + (l >> 4) * 8;
        const int nn = ct * 16 + (l & 15);
        ushort4 v0, v1;
        const float* wp = W + (size_t)rel * D * D + (size_t)kbase * D + nn;
        v0.x = f2bf(wp[0 * D]); v0.y = f2bf(wp[1 * D]);
        v0.z = f2bf(wp[2 * D]); v0.w = f2bf(wp[3 * D]);
        v1.x = f2bf(wp[4 * D]); v1.y = f2bf(wp[5 * D]);
        v1.z = f2bf(wp[6 * D]); v1.w = f2bf(wp[7 * D]);
        ushort4* op = (ushort4*)(Wsw + (size_t)gid * 8);
        op[0] = v0;
        op[1] = v1;
    }

    const int n4 = N * D / 4;
    for (int i = gtid; i < n4; i += gsize) {
        const float4 v = ((const float4*)x)[i];
        ushort4 o;
        o.x = f2bf(v.x); o.y = f2bf(v.y); o.z = f2bf(v.z); o.w = f2bf(v.w);
        ((ushort4*)xB)[i] = o;
    }
}

// ---------------------------------------------------------------------------
// Fused aggregate + GEMM + bias + ReLU. ONE block per bin (M=64 dsts).
//  A) read part[] ONCE: histogram + raw staging into the idle agg region
//     (8 KB >= 6.7 KB); scan; LDS counting-sort into sh_s.
//  B/C) 2 half-tiles (M=32) x 4 rel-quarters: gather rel q of half h ->
//     bf16 LDS tile agg[32][128] (XOR-swizzled), sync, 4-kb MFMA pass into
//     per-half VGPR acc[2][2], sync; per-half epilogue (bias+ReLU+store).
// LDS 17.9 KB -> 8 blocks/CU (wave-limit cap). Edge list stays in LDS.
// ---------------------------------------------------------------------------
__global__ __launch_bounds__(256, 8) void agg_gemm_kernel(
    const unsigned int* __restrict__ part,
    const int* __restrict__ binCnt,
    const unsigned short* __restrict__ xB,   // [N][128] bf16
    const unsigned short* __restrict__ Wsw,  // [16][8][64][8] bf16
    const float* __restrict__ bsum,          // [128]
    float* __restrict__ out,                 // [N][128]
    int N)
{
    __shared__ int sh_s[BCAP];                         // 6.7 KB sorted src
    __shared__ int hist[NBK];                          // 1 KB
    __shared__ int scanbuf[NBK];                       // 1 KB
    __shared__ int offl[NBK + 1];                      // 1 KB
    __shared__ __align__(16) unsigned short agg[32 * 128];  // 8 KB, swizzled
    // phase-A overlay: raw entry staging in the idle agg region (6.7 <= 8 KB)
    unsigned int* raw = (unsigned int*)agg;

    const int t    = threadIdx.x;
    const int b    = blockIdx.x;
    const size_t base = (size_t)b * BCAP;
    const int cnt  = min(binCnt[b], BCAP);
    const int dst0 = b * 64;

    // ---- A: histogram + raw staging (single part[] read) ----
    hist[t] = 0;
    __syncthreads();
    for (int i = t; i < cnt; i += 256) {
        const unsigned v = part[base + i];
        raw[i] = v;
        atomicAdd(&hist[v >> 17], 1);
    }
    __syncthreads();

    const int myc = hist[t];
    scanbuf[t] = myc;
    __syncthreads();
    for (int off = 1; off < 256; off <<= 1) {
        int v = (t >= off) ? scanbuf[t - off] : 0;
        __syncthreads();
        scanbuf[t] += v;
        __syncthreads();
    }
    offl[t] = scanbuf[t] - myc;
    if (t == 255) offl[256] = scanbuf[255];
    hist[t] = scanbuf[t] - myc;           // cursor
    __syncthreads();

    // sort: LDS raw -> LDS sh_s
    for (int i = t; i < cnt; i += 256) {
        const unsigned v = raw[i];
        const int pos = atomicAdd(&hist[v >> 17], 1);
        sh_s[pos] = (int)(v & 0x1FFFF);
    }
    __syncthreads();

    // ---- B/C: 2 halves x 4 rel-quarters of gather -> LDS -> MFMA ----
    const int c    = t & 15;        // 16-byte chunk index (8 bf16)
    const int team = t >> 4;        // unit slot 0..15

    const int wv   = t >> 6;
    const int l    = t & 63;
    const int lrow = l & 15;
    const int quad = l >> 4;
    const int ct0  = wv * 2;        // each wave: 2 col-tiles x 2 row-tiles

    #define ACCUM(v)                                        \
        accL[0] += __uint_as_float((v).x << 16);            \
        accH[0] += __uint_as_float((v).x & 0xffff0000u);    \
        accL[1] += __uint_as_float((v).y << 16);            \
        accH[1] += __uint_as_float((v).y & 0xffff0000u);    \
        accL[2] += __uint_as_float((v).z << 16);            \
        accH[2] += __uint_as_float((v).z & 0xffff0000u);    \
        accL[3] += __uint_as_float((v).w << 16);            \
        accH[3] += __uint_as_float((v).w & 0xffff0000u);

    #pragma unroll 1
    for (int h = 0; h < 2; ++h) {
        f32x4 acc[2][2] = {};

        #pragma unroll 1
        for (int q = 0; q < NREL; ++q) {
            if (h | q) __syncthreads();   // previous MFMA pass done with agg

            // gather: 32 buckets of half h, rel q (bucket = (h*32+ld)*4+q)
            for (int ld = team; ld < 32; ld += 16) {
                const int bkt = (h * 32 + ld) * 4 + q;
                const int beg = offl[bkt];
                const int end = offl[bkt + 1];
                const float inv = 1.0f / fmaxf((float)(end - beg), 1.0f);

                float accL[4] = {0.f, 0.f, 0.f, 0.f};
                float accH[4] = {0.f, 0.f, 0.f, 0.f};

                int j = beg;
                for (; j + 3 < end; j += 4) {
                    const int s0 = sh_s[j];
                    const int s1 = sh_s[j + 1];
                    const int s2 = sh_s[j + 2];
                    const int s3 = sh_s[j + 3];
                    const uint4 v0 = *(const uint4*)(xB + (size_t)s0 * D + c * 8);
                    const uint4 v1 = *(const uint4*)(xB + (size_t)s1 * D + c * 8);
                    const uint4 v2 = *(const uint4*)(xB + (size_t)s2 * D + c * 8);
                    const uint4 v3 = *(const uint4*)(xB + (size_t)s3 * D + c * 8);
                    ACCUM(v0) ACCUM(v1) ACCUM(v2) ACCUM(v3)
                }
                for (; j < end; ++j) {
                    const uint4 v0 = *(const uint4*)(xB + (size_t)sh_s[j] * D + c * 8);
                    ACCUM(v0)
                }

                uint4 o;
                o.x = ((unsigned)f2bf(accH[0] * inv) << 16) | f2bf(accL[0] * inv);
                o.y = ((unsigned)f2bf(accH[1] * inv) << 16) | f2bf(accL[1] * inv);
                o.z = ((unsigned)f2bf(accH[2] * inv) << 16) | f2bf(accL[2] * inv);
                o.w = ((unsigned)f2bf(accH[3] * inv) << 16) | f2bf(accL[3] * inv);
                // row ld (256 B stride), chunk c, XOR-swizzled per row
                const int byte = (c * 16) ^ ((ld & 7) << 4);
                *(uint4*)((char*)agg + ld * 256 + byte) = o;
            }
            __syncthreads();

            // MFMA pass: K-quarter q = kb q*4 .. q*4+3, rows of half h
            #pragma unroll
            for (int kbl = 0; kbl < 4; ++kbl) {
                short8 a[2];
                #pragma unroll
                for (int rt = 0; rt < 2; ++rt) {
                    const int row  = rt * 16 + lrow;
                    const int byte = (kbl * 64 + quad * 16) ^ ((row & 7) << 4);
                    a[rt] = *(const short8*)((const char*)agg + row * 256 + byte);
                }
                const int kb = q * 4 + kbl;
                const unsigned short* wp = Wsw + ((size_t)(kb * 8 + ct0) * 64 + l) * 8;
                const short8 b0 = *(const short8*)wp;
                const short8 b1 = *(const short8*)(wp + 64 * 8);
                acc[0][0] = __builtin_amdgcn_mfma_f32_16x16x32_bf16(a[0], b0, acc[0][0], 0, 0, 0);
                acc[1][0] = __builtin_amdgcn_mfma_f32_16x16x32_bf16(a[1], b0, acc[1][0], 0, 0, 0);
                acc[0][1] = __builtin_amdgcn_mfma_f32_16x16x32_bf16(a[0], b1, acc[0][1], 0, 0, 0);
                acc[1][1] = __builtin_amdgcn_mfma_f32_16x16x32_bf16(a[1], b1, acc[1][1], 0, 0, 0);
            }
        }

        // ---- epilogue for half h: bias + ReLU + store ----
        #pragma unroll
        for (int ci = 0; ci < 2; ++ci) {
            const int col = (ct0 + ci) * 16 + lrow;
            const float bv = bsum[col];
            #pragma unroll
            for (int rt = 0; rt < 2; ++rt) {
                #pragma unroll
                for (int e = 0; e < 4; ++e) {
                    const int row = dst0 + h * 32 + rt * 16 + quad * 4 + e;
                    if (row < N)
                        out[(size_t)row * D + col] = fmaxf(acc[rt][ci][e] + bv, 0.f);
                }
            }
        }
    }
    #undef ACCUM
}

static inline size_t align_up(size_t v, size_t a) { return (v + a - 1) & ~(a - 1); }

extern "C" void kernel_launch(void* const* d_in, const int* in_sizes, int n_in,
                              void* d_out, int out_size, void* d_ws, size_t ws_size,
                              hipStream_t stream)
{
    const float* x    = (const float*)d_in[0];   // [N, 128]
    const float* W    = (const float*)d_in[1];   // [4, 128, 128]
    const float* bias = (const float*)d_in[2];   // [4, 128]
    const int* src    = (const int*)d_in[3];     // [4, E]
    const int* dst    = (const int*)d_in[4];     // [4, E]
    float* out        = (float*)d_out;           // [N, 128]

    const int N = in_sizes[0] / D;               // 100000
    const int E = in_sizes[3] / NREL;            // 500000
    const int nG = NREL * N;                     // 400000 buckets
    const int totalE = NREL * E;                 // 2000000 edges
    const int nbins  = (nG + NBK - 1) >> BINSHIFT;  // 1563

    char* w = (char*)d_ws;
    int* binCnt = (int*)w;            w += align_up((size_t)nbins * 4, 256);
    unsigned int* part = (unsigned int*)w;     w += align_up((size_t)nbins * BCAP * 4, 256);
    unsigned short* Wsw = (unsigned short*)w;  w += align_up((size_t)512 * D * 2, 256);
    float* bsum = (float*)w;          w += align_up((size_t)D * 4, 256);
    unsigned short* xB = (unsigned short*)w;   // [N][128] bf16

    const int p1_blocks = 2048;

    hipMemsetAsync(binCnt, 0, (size_t)nbins * sizeof(int), stream);
    part1prep_kernel<<<p1_blocks, 256, 0, stream>>>(
        x, W, bias, src, dst, binCnt, part, xB, Wsw, bsum, E, N, nbins, totalE);
    agg_gemm_kernel<<<nbins, 256, 0, stream>>>(part, binCnt, xB, Wsw, bsum, out, N);
}

// Round 6
// 292.177 us; speedup vs baseline: 1.6688x; 1.6688x over previous
//
#include <hip/hip_runtime.h>

#define D 128          // D_IN == D_OUT == 128
#define NREL 4
#define BINSHIFT 8     // 256 buckets per coarse bin
#define NBK 256        // buckets per bin
#define BCAP 1664      // edge capacity per bin window (mean 1280, +10.7 sigma)
#define BPAD 32        // ints per bin counter slot (128 B = 1 L2 line) — kills
                       // false sharing: 16 counters/line serialized ALL atomics

typedef __attribute__((ext_vector_type(8))) short short8;
typedef __attribute__((ext_vector_type(4))) float f32x4;

static __device__ inline unsigned short f2bf(float f) {
    unsigned int u = __float_as_uint(f);
    u += 0x7fffu + ((u >> 16) & 1u);   // round-to-nearest-even
    return (unsigned short)(u >> 16);
}

// ---------------------------------------------------------------------------
// part1 + prep, scatter edition. Bucket key DST-MAJOR: g = dst*4 + rel, so
// one bin (256 buckets) = 64 dsts x 4 rels = one M=64, K=512 output tile.
//  A) grid-stride DIRECT scatter: pos = atomicAdd(binCnt[bin*BPAD]), write
//     entry to part[bin*BCAP+pos]. Counters padded to one per 128 B line —
//     round-5 counters shared 16/line and line-serialized atomics made this
//     loop 305 us; padded, the per-line chain is 1280*~35cy ~= 19 us.
//  B) grid-stride xcast (f32->bf16), W swizzle, bias sum.
// Entry = src | (g&255)<<17, bin = g>>8. LDS = 0 -> occupancy-unbound.
// ---------------------------------------------------------------------------
__global__ __launch_bounds__(256) void part1prep_kernel(
    const float* __restrict__ x,      // [N][128]
    const float* __restrict__ W,      // [4][128][128]
    const float* __restrict__ bias,   // [4][128]
    const int* __restrict__ src, const int* __restrict__ dst,
    int* __restrict__ binCnt, unsigned int* __restrict__ part,
    unsigned short* __restrict__ xB,  // [N][128] bf16
    unsigned short* __restrict__ Wsw, // [16][8][64][8] bf16
    float* __restrict__ bsum,         // [128]
    int E, int N, int nbins, int total)
{
    const int t     = threadIdx.x;
    const int gtid  = blockIdx.x * 256 + t;
    const int gsize = gridDim.x * 256;
    const int E2 = 2 * E, E3 = 3 * E;

    // ---- A: direct scatter, 4 edges/thread via int4 loads ----
    const int nq = total >> 2;
    for (int i = gtid; i < nq; i += gsize) {
        const int e = i * 4;
        const int4 s4 = ((const int4*)src)[i];
        const int4 d4 = ((const int4*)dst)[i];
        #pragma unroll
        for (int k = 0; k < 4; ++k) {
            const int ek = e + k;
            const int sk = (k == 0) ? s4.x : (k == 1) ? s4.y : (k == 2) ? s4.z : s4.w;
            const int dk = (k == 0) ? d4.x : (k == 1) ? d4.y : (k == 2) ? d4.z : d4.w;
            const int r  = (ek >= E) + (ek >= E2) + (ek >= E3);
            const int g  = (dk << 2) | r;               // DST-MAJOR key
            const unsigned entry = (unsigned)sk | ((unsigned)(g & (NBK - 1)) << 17);
            const int bin = g >> BINSHIFT;
            const int pos = atomicAdd(&binCnt[bin * BPAD], 1);
            if (pos < BCAP)                             // 10.7-sigma guard
                part[(size_t)bin * BCAP + pos] = entry;
        }
    }
    for (int e = (nq << 2) + gtid; e < total; e += gsize) {   // tail (total%4)
        const int r  = (e >= E) + (e >= E2) + (e >= E3);
        const int g  = (dst[e] << 2) | r;
        const unsigned entry = (unsigned)src[e] | ((unsigned)(g & (NBK - 1)) << 17);
        const int bin = g >> BINSHIFT;
        const int pos = atomicAdd(&binCnt[bin * BPAD], 1);
        if (pos < BCAP)
            part[(size_t)bin * BCAP + pos] = entry;
    }

    // ---- B: prep (grid-stride) ----
    if (gtid < D)
        bsum[gtid] = bias[gtid] + bias[D + gtid] + bias[2 * D + gtid] + bias[3 * D + gtid];

    for (int gid = gtid; gid < 8192; gid += gsize) {
        const int l   = gid & 63;
        const int ct  = (gid >> 6) & 7;
        const int kb  = gid >> 9;
        const int rel = kb >> 2;
        const int kbase = (kb & 3) * 32 + (l >> 4) * 8;
        const int nn = ct * 16 + (l & 15);
        ushort4 v0, v1;
        const float* wp = W + (size_t)rel * D * D + (size_t)kbase * D + nn;
        v0.x = f2bf(wp[0 * D]); v0.y = f2bf(wp[1 * D]);
        v0.z = f2bf(wp[2 * D]); v0.w = f2bf(wp[3 * D]);
        v1.x = f2bf(wp[4 * D]); v1.y = f2bf(wp[5 * D]);
        v1.z = f2bf(wp[6 * D]); v1.w = f2bf(wp[7 * D]);
        ushort4* op = (ushort4*)(Wsw + (size_t)gid * 8);
        op[0] = v0;
        op[1] = v1;
    }

    const int n4 = N * D / 4;
    for (int i = gtid; i < n4; i += gsize) {
        const float4 v = ((const float4*)x)[i];
        ushort4 o;
        o.x = f2bf(v.x); o.y = f2bf(v.y); o.z = f2bf(v.z); o.w = f2bf(v.w);
        ((ushort4*)xB)[i] = o;
    }
}

// ---------------------------------------------------------------------------
// Fused aggregate + GEMM + bias + ReLU. ONE block per bin (M=64 dsts).
//  A) read part[] ONCE: histogram + raw staging into the idle agg region
//     (8 KB >= 6.7 KB); scan; LDS counting-sort into sh_s.
//  B/C) 2 half-tiles (M=32) x 4 rel-quarters: gather rel q of half h ->
//     bf16 LDS tile agg[32][128] (XOR-swizzled), sync, 4-kb MFMA pass into
//     per-half VGPR acc[2][2], sync; per-half epilogue (bias+ReLU+store).
// LDS 17.9 KB -> 8 blocks/CU (wave-limit cap). Edge list stays in LDS.
// ---------------------------------------------------------------------------
__global__ __launch_bounds__(256, 8) void agg_gemm_kernel(
    const unsigned int* __restrict__ part,
    const int* __restrict__ binCnt,
    const unsigned short* __restrict__ xB,   // [N][128] bf16
    const unsigned short* __restrict__ Wsw,  // [16][8][64][8] bf16
    const float* __restrict__ bsum,          // [128]
    float* __restrict__ out,                 // [N][128]
    int N)
{
    __shared__ int sh_s[BCAP];                         // 6.7 KB sorted src
    __shared__ int hist[NBK];                          // 1 KB
    __shared__ int scanbuf[NBK];                       // 1 KB
    __shared__ int offl[NBK + 1];                      // 1 KB
    __shared__ __align__(16) unsigned short agg[32 * 128];  // 8 KB, swizzled
    // phase-A overlay: raw entry staging in the idle agg region (6.7 <= 8 KB)
    unsigned int* raw = (unsigned int*)agg;

    const int t    = threadIdx.x;
    const int b    = blockIdx.x;
    const size_t base = (size_t)b * BCAP;
    const int cnt  = min(binCnt[b * BPAD], BCAP);
    const int dst0 = b * 64;

    // ---- A: histogram + raw staging (single part[] read) ----
    hist[t] = 0;
    __syncthreads();
    for (int i = t; i < cnt; i += 256) {
        const unsigned v = part[base + i];
        raw[i] = v;
        atomicAdd(&hist[v >> 17], 1);
    }
    __syncthreads();

    const int myc = hist[t];
    scanbuf[t] = myc;
    __syncthreads();
    for (int off = 1; off < 256; off <<= 1) {
        int v = (t >= off) ? scanbuf[t - off] : 0;
        __syncthreads();
        scanbuf[t] += v;
        __syncthreads();
    }
    offl[t] = scanbuf[t] - myc;
    if (t == 255) offl[256] = scanbuf[255];
    hist[t] = scanbuf[t] - myc;           // cursor
    __syncthreads();

    // sort: LDS raw -> LDS sh_s
    for (int i = t; i < cnt; i += 256) {
        const unsigned v = raw[i];
        const int pos = atomicAdd(&hist[v >> 17], 1);
        sh_s[pos] = (int)(v & 0x1FFFF);
    }
    __syncthreads();

    // ---- B/C: 2 halves x 4 rel-quarters of gather -> LDS -> MFMA ----
    const int c    = t & 15;        // 16-byte chunk index (8 bf16)
    const int team = t >> 4;        // unit slot 0..15

    const int wv   = t >> 6;
    const int l    = t & 63;
    const int lrow = l & 15;
    const int quad = l >> 4;
    const int ct0  = wv * 2;        // each wave: 2 col-tiles x 2 row-tiles

    #define ACCUM(v)                                        \
        accL[0] += __uint_as_float((v).x << 16);            \
        accH[0] += __uint_as_float((v).x & 0xffff0000u);    \
        accL[1] += __uint_as_float((v).y << 16);            \
        accH[1] += __uint_as_float((v).y & 0xffff0000u);    \
        accL[2] += __uint_as_float((v).z << 16);            \
        accH[2] += __uint_as_float((v).z & 0xffff0000u);    \
        accL[3] += __uint_as_float((v).w << 16);            \
        accH[3] += __uint_as_float((v).w & 0xffff0000u);

    #pragma unroll 1
    for (int h = 0; h < 2; ++h) {
        f32x4 acc[2][2] = {};

        #pragma unroll 1
        for (int q = 0; q < NREL; ++q) {
            if (h | q) __syncthreads();   // previous MFMA pass done with agg

            // gather: 32 buckets of half h, rel q (bucket = (h*32+ld)*4+q)
            for (int ld = team; ld < 32; ld += 16) {
                const int bkt = (h * 32 + ld) * 4 + q;
                const int beg = offl[bkt];
                const int end = offl[bkt + 1];
                const float inv = 1.0f / fmaxf((float)(end - beg), 1.0f);

                float accL[4] = {0.f, 0.f, 0.f, 0.f};
                float accH[4] = {0.f, 0.f, 0.f, 0.f};

                int j = beg;
                for (; j + 3 < end; j += 4) {
                    const int s0 = sh_s[j];
                    const int s1 = sh_s[j + 1];
                    const int s2 = sh_s[j + 2];
                    const int s3 = sh_s[j + 3];
                    const uint4 v0 = *(const uint4*)(xB + (size_t)s0 * D + c * 8);
                    const uint4 v1 = *(const uint4*)(xB + (size_t)s1 * D + c * 8);
                    const uint4 v2 = *(const uint4*)(xB + (size_t)s2 * D + c * 8);
                    const uint4 v3 = *(const uint4*)(xB + (size_t)s3 * D + c * 8);
                    ACCUM(v0) ACCUM(v1) ACCUM(v2) ACCUM(v3)
                }
                for (; j < end; ++j) {
                    const uint4 v0 = *(const uint4*)(xB + (size_t)sh_s[j] * D + c * 8);
                    ACCUM(v0)
                }

                uint4 o;
                o.x = ((unsigned)f2bf(accH[0] * inv) << 16) | f2bf(accL[0] * inv);
                o.y = ((unsigned)f2bf(accH[1] * inv) << 16) | f2bf(accL[1] * inv);
                o.z = ((unsigned)f2bf(accH[2] * inv) << 16) | f2bf(accL[2] * inv);
                o.w = ((unsigned)f2bf(accH[3] * inv) << 16) | f2bf(accL[3] * inv);
                // row ld (256 B stride), chunk c, XOR-swizzled per row
                const int byte = (c * 16) ^ ((ld & 7) << 4);
                *(uint4*)((char*)agg + ld * 256 + byte) = o;
            }
            __syncthreads();

            // MFMA pass: K-quarter q = kb q*4 .. q*4+3, rows of half h
            #pragma unroll
            for (int kbl = 0; kbl < 4; ++kbl) {
                short8 a[2];
                #pragma unroll
                for (int rt = 0; rt < 2; ++rt) {
                    const int row  = rt * 16 + lrow;
                    const int byte = (kbl * 64 + quad * 16) ^ ((row & 7) << 4);
                    a[rt] = *(const short8*)((const char*)agg + row * 256 + byte);
                }
                const int kb = q * 4 + kbl;
                const unsigned short* wp = Wsw + ((size_t)(kb * 8 + ct0) * 64 + l) * 8;
                const short8 b0 = *(const short8*)wp;
                const short8 b1 = *(const short8*)(wp + 64 * 8);
                acc[0][0] = __builtin_amdgcn_mfma_f32_16x16x32_bf16(a[0], b0, acc[0][0], 0, 0, 0);
                acc[1][0] = __builtin_amdgcn_mfma_f32_16x16x32_bf16(a[1], b0, acc[1][0], 0, 0, 0);
                acc[0][1] = __builtin_amdgcn_mfma_f32_16x16x32_bf16(a[0], b1, acc[0][1], 0, 0, 0);
                acc[1][1] = __builtin_amdgcn_mfma_f32_16x16x32_bf16(a[1], b1, acc[1][1], 0, 0, 0);
            }
        }

        // ---- epilogue for half h: bias + ReLU + store ----
        #pragma unroll
        for (int ci = 0; ci < 2; ++ci) {
            const int col = (ct0 + ci) * 16 + lrow;
            const float bv = bsum[col];
            #pragma unroll
            for (int rt = 0; rt < 2; ++rt) {
                #pragma unroll
                for (int e = 0; e < 4; ++e) {
                    const int row = dst0 + h * 32 + rt * 16 + quad * 4 + e;
                    if (row < N)
                        out[(size_t)row * D + col] = fmaxf(acc[rt][ci][e] + bv, 0.f);
                }
            }
        }
    }
    #undef ACCUM
}

static inline size_t align_up(size_t v, size_t a) { return (v + a - 1) & ~(a - 1); }

extern "C" void kernel_launch(void* const* d_in, const int* in_sizes, int n_in,
                              void* d_out, int out_size, void* d_ws, size_t ws_size,
                              hipStream_t stream)
{
    const float* x    = (const float*)d_in[0];   // [N, 128]
    const float* W    = (const float*)d_in[1];   // [4, 128, 128]
    const float* bias = (const float*)d_in[2];   // [4, 128]
    const int* src    = (const int*)d_in[3];     // [4, E]
    const int* dst    = (const int*)d_in[4];     // [4, E]
    float* out        = (float*)d_out;           // [N, 128]

    const int N = in_sizes[0] / D;               // 100000
    const int E = in_sizes[3] / NREL;            // 500000
    const int nG = NREL * N;                     // 400000 buckets
    const int totalE = NREL * E;                 // 2000000 edges
    const int nbins  = (nG + NBK - 1) >> BINSHIFT;  // 1563

    char* w = (char*)d_ws;
    int* binCnt = (int*)w;            w += align_up((size_t)nbins * BPAD * 4, 256);
    unsigned int* part = (unsigned int*)w;     w += align_up((size_t)nbins * BCAP * 4, 256);
    unsigned short* Wsw = (unsigned short*)w;  w += align_up((size_t)512 * D * 2, 256);
    float* bsum = (float*)w;          w += align_up((size_t)D * 4, 256);
    unsigned short* xB = (unsigned short*)w;   // [N][128] bf16

    const int p1_blocks = 2048;

    hipMemsetAsync(binCnt, 0, (size_t)nbins * BPAD * sizeof(int), stream);
    part1prep_kernel<<<p1_blocks, 256, 0, stream>>>(
        x, W, bias, src, dst, binCnt, part, xB, Wsw, bsum, E, N, nbins, totalE);
    agg_gemm_kernel<<<nbins, 256, 0, stream>>>(part, binCnt, xB, Wsw, bsum, out, N);
}

// Round 7
// 284.441 us; speedup vs baseline: 1.7141x; 1.0272x over previous
//
#include <hip/hip_runtime.h>

#define D 128          // D_IN == D_OUT == 128
#define NREL 4
#define BINSHIFT 8     // 256 buckets per coarse bin
#define NBK 256        // buckets per bin
#define SUBW 8         // sub-windows (and sub-counters) per bin
#define SCAP 256       // entries per sub-window (mean 160, +7.6 sigma)
#define WCAP (SUBW * SCAP)   // 2048 entries per bin window
#define BPAD 32        // ints per counter slot (128 B = 1 L2 line). Round 5/6
                       // showed same-LINE atomics serialize at ~225 cy each:
                       // 16 counters/line = 305 us; 1/line = 125 us; 8 sub-
                       // counters/bin cut the per-chain length 8x -> ~15 us.

typedef __attribute__((ext_vector_type(8))) short short8;
typedef __attribute__((ext_vector_type(4))) float f32x4;

static __device__ inline unsigned short f2bf(float f) {
    unsigned int u = __float_as_uint(f);
    u += 0x7fffu + ((u >> 16) & 1u);   // round-to-nearest-even
    return (unsigned short)(u >> 16);
}

// ---------------------------------------------------------------------------
// part1 + prep, scatter edition. Bucket key DST-MAJOR: g = dst*4 + rel, so
// one bin (256 buckets) = 64 dsts x 4 rels = one M=64, K=512 output tile.
//  A) grid-stride DIRECT scatter with sub-bucketed counters: sub-counter
//     s = blockIdx&7 (correlates with XCD round-robin -> mostly-local
//     atomics), pos = atomicAdd(binCnt[(bin*8+s)*BPAD]), write entry to
//     part[bin*WCAP + s*SCAP + pos]. Chain/counter ~160 atomics.
//  B) grid-stride xcast (f32->bf16), W swizzle, bias sum.
// Entry = src | (g&255)<<17, bin = g>>8. LDS = 0 -> occupancy-unbound.
// ---------------------------------------------------------------------------
__global__ __launch_bounds__(256) void part1prep_kernel(
    const float* __restrict__ x,      // [N][128]
    const float* __restrict__ W,      // [4][128][128]
    const float* __restrict__ bias,   // [4][128]
    const int* __restrict__ src, const int* __restrict__ dst,
    int* __restrict__ binCnt, unsigned int* __restrict__ part,
    unsigned short* __restrict__ xB,  // [N][128] bf16
    unsigned short* __restrict__ Wsw, // [16][8][64][8] bf16
    float* __restrict__ bsum,         // [128]
    int E, int N, int nbins, int total)
{
    const int t     = threadIdx.x;
    const int gtid  = blockIdx.x * 256 + t;
    const int gsize = gridDim.x * 256;
    const int E2 = 2 * E, E3 = 3 * E;
    const int sub = blockIdx.x & (SUBW - 1);      // per-block sub-counter

    // ---- A: direct scatter, 4 edges/thread via int4 loads ----
    const int nq = total >> 2;
    for (int i = gtid; i < nq; i += gsize) {
        const int e = i * 4;
        const int4 s4 = ((const int4*)src)[i];
        const int4 d4 = ((const int4*)dst)[i];
        #pragma unroll
        for (int k = 0; k < 4; ++k) {
            const int ek = e + k;
            const int sk = (k == 0) ? s4.x : (k == 1) ? s4.y : (k == 2) ? s4.z : s4.w;
            const int dk = (k == 0) ? d4.x : (k == 1) ? d4.y : (k == 2) ? d4.z : d4.w;
            const int r  = (ek >= E) + (ek >= E2) + (ek >= E3);
            const int g  = (dk << 2) | r;               // DST-MAJOR key
            const unsigned entry = (unsigned)sk | ((unsigned)(g & (NBK - 1)) << 17);
            const int bin = g >> BINSHIFT;
            const int pos = atomicAdd(&binCnt[(bin * SUBW + sub) * BPAD], 1);
            if (pos < SCAP)                             // 7.6-sigma guard
                part[(size_t)bin * WCAP + sub * SCAP + pos] = entry;
        }
    }
    for (int e = (nq << 2) + gtid; e < total; e += gsize) {   // tail (total%4)
        const int r  = (e >= E) + (e >= E2) + (e >= E3);
        const int g  = (dst[e] << 2) | r;
        const unsigned entry = (unsigned)src[e] | ((unsigned)(g & (NBK - 1)) << 17);
        const int bin = g >> BINSHIFT;
        const int pos = atomicAdd(&binCnt[(bin * SUBW + sub) * BPAD], 1);
        if (pos < SCAP)
            part[(size_t)bin * WCAP + sub * SCAP + pos] = entry;
    }

    // ---- B: prep (grid-stride) ----
    if (gtid < D)
        bsum[gtid] = bias[gtid] + bias[D + gtid] + bias[2 * D + gtid] + bias[3 * D + gtid];

    for (int gid = gtid; gid < 8192; gid += gsize) {
        const int l   = gid & 63;
        const int ct  = (gid >> 6) & 7;
        const int kb  = gid >> 9;
        const int rel = kb >> 2;
        const int kbase = (kb & 3) * 32 + (l >> 4) * 8;
        const int nn = ct * 16 + (l & 15);
        ushort4 v0, v1;
        const float* wp = W + (size_t)rel * D * D + (size_t)kbase * D + nn;
        v0.x = f2bf(wp[0 * D]); v0.y = f2bf(wp[1 * D]);
        v0.z = f2bf(wp[2 * D]); v0.w = f2bf(wp[3 * D]);
        v1.x = f2bf(wp[4 * D]); v1.y = f2bf(wp[5 * D]);
        v1.z = f2bf(wp[6 * D]); v1.w = f2bf(wp[7 * D]);
        ushort4* op = (ushort4*)(Wsw + (size_t)gid * 8);
        op[0] = v0;
        op[1] = v1;
    }

    const int n4 = N * D / 4;
    for (int i = gtid; i < n4; i += gsize) {
        const float4 v = ((const float4*)x)[i];
        ushort4 o;
        o.x = f2bf(v.x); o.y = f2bf(v.y); o.z = f2bf(v.z); o.w = f2bf(v.w);
        ((ushort4*)xB)[i] = o;
    }
}

// ---------------------------------------------------------------------------
// Fused aggregate + GEMM + bias + ReLU. ONE block per bin (M=64 dsts).
//  A) read the bin's 8 sub-windows ONCE: histogram + stage back-to-back into
//     the idle agg region (8 KB = 2048 entries = structural max); scan;
//     LDS counting-sort into sh_s[2048].
//  B/C) 2 half-tiles (M=32) x 4 rel-quarters: gather rel q of half h ->
//     bf16 LDS tile agg[32][128] (XOR-swizzled), sync, 4-kb MFMA pass into
//     per-half VGPR acc[2][2], sync; per-half epilogue (bias+ReLU+store).
// LDS 19.5 KB -> 8 blocks/CU (wave-limit cap). Edge list stays in LDS.
// ---------------------------------------------------------------------------
__global__ __launch_bounds__(256, 8) void agg_gemm_kernel(
    const unsigned int* __restrict__ part,
    const int* __restrict__ binCnt,
    const unsigned short* __restrict__ xB,   // [N][128] bf16
    const unsigned short* __restrict__ Wsw,  // [16][8][64][8] bf16
    const float* __restrict__ bsum,          // [128]
    float* __restrict__ out,                 // [N][128]
    int N)
{
    __shared__ int sh_s[WCAP];                         // 8 KB sorted src
    __shared__ int hist[NBK];                          // 1 KB
    __shared__ int scanbuf[NBK];                       // 1 KB
    __shared__ int offl[NBK + 1];                      // 1 KB
    __shared__ __align__(16) unsigned short agg[32 * 128];  // 8 KB, swizzled
    // phase-A overlay: raw entry staging in the idle agg region (8 KB)
    unsigned int* raw = (unsigned int*)agg;

    const int t    = threadIdx.x;
    const int b    = blockIdx.x;
    const int dst0 = b * 64;

    // ---- A: histogram + raw staging (single part[] read, 8 sub-windows) ---
    hist[t] = 0;
    __syncthreads();
    int cs[SUBW];
    #pragma unroll
    for (int s = 0; s < SUBW; ++s)
        cs[s] = min(binCnt[(b * SUBW + s) * BPAD], SCAP);

    int cnt = 0;
    #pragma unroll
    for (int s = 0; s < SUBW; ++s) {
        const unsigned int* wp = part + (size_t)b * WCAP + s * SCAP;
        for (int i = t; i < cs[s]; i += 256) {
            const unsigned v = wp[i];
            raw[cnt + i] = v;
            atomicAdd(&hist[v >> 17], 1);
        }
        cnt += cs[s];
    }
    __syncthreads();

    const int myc = hist[t];
    scanbuf[t] = myc;
    __syncthreads();
    for (int off = 1; off < 256; off <<= 1) {
        int v = (t >= off) ? scanbuf[t - off] : 0;
        __syncthreads();
        scanbuf[t] += v;
        __syncthreads();
    }
    offl[t] = scanbuf[t] - myc;
    if (t == 255) offl[256] = scanbuf[255];
    hist[t] = scanbuf[t] - myc;           // cursor
    __syncthreads();

    // sort: LDS raw -> LDS sh_s
    for (int i = t; i < cnt; i += 256) {
        const unsigned v = raw[i];
        const int pos = atomicAdd(&hist[v >> 17], 1);
        sh_s[pos] = (int)(v & 0x1FFFF);
    }
    __syncthreads();

    // ---- B/C: 2 halves x 4 rel-quarters of gather -> LDS -> MFMA ----
    const int c    = t & 15;        // 16-byte chunk index (8 bf16)
    const int team = t >> 4;        // unit slot 0..15

    const int wv   = t >> 6;
    const int l    = t & 63;
    const int lrow = l & 15;
    const int quad = l >> 4;
    const int ct0  = wv * 2;        // each wave: 2 col-tiles x 2 row-tiles

    #define ACCUM(v)                                        \
        accL[0] += __uint_as_float((v).x << 16);            \
        accH[0] += __uint_as_float((v).x & 0xffff0000u);    \
        accL[1] += __uint_as_float((v).y << 16);            \
        accH[1] += __uint_as_float((v).y & 0xffff0000u);    \
        accL[2] += __uint_as_float((v).z << 16);            \
        accH[2] += __uint_as_float((v).z & 0xffff0000u);    \
        accL[3] += __uint_as_float((v).w << 16);            \
        accH[3] += __uint_as_float((v).w & 0xffff0000u);

    #pragma unroll 1
    for (int h = 0; h < 2; ++h) {
        f32x4 acc[2][2] = {};

        #pragma unroll 1
        for (int q = 0; q < NREL; ++q) {
            if (h | q) __syncthreads();   // previous MFMA pass done with agg

            // gather: 32 buckets of half h, rel q (bucket = (h*32+ld)*4+q)
            for (int ld = team; ld < 32; ld += 16) {
                const int bkt = (h * 32 + ld) * 4 + q;
                const int beg = offl[bkt];
                const int end = offl[bkt + 1];
                const float inv = 1.0f / fmaxf((float)(end - beg), 1.0f);

                float accL[4] = {0.f, 0.f, 0.f, 0.f};
                float accH[4] = {0.f, 0.f, 0.f, 0.f};

                int j = beg;
                for (; j + 3 < end; j += 4) {
                    const int s0 = sh_s[j];
                    const int s1 = sh_s[j + 1];
                    const int s2 = sh_s[j + 2];
                    const int s3 = sh_s[j + 3];
                    const uint4 v0 = *(const uint4*)(xB + (size_t)s0 * D + c * 8);
                    const uint4 v1 = *(const uint4*)(xB + (size_t)s1 * D + c * 8);
                    const uint4 v2 = *(const uint4*)(xB + (size_t)s2 * D + c * 8);
                    const uint4 v3 = *(const uint4*)(xB + (size_t)s3 * D + c * 8);
                    ACCUM(v0) ACCUM(v1) ACCUM(v2) ACCUM(v3)
                }
                for (; j < end; ++j) {
                    const uint4 v0 = *(const uint4*)(xB + (size_t)sh_s[j] * D + c * 8);
                    ACCUM(v0)
                }

                uint4 o;
                o.x = ((unsigned)f2bf(accH[0] * inv) << 16) | f2bf(accL[0] * inv);
                o.y = ((unsigned)f2bf(accH[1] * inv) << 16) | f2bf(accL[1] * inv);
                o.z = ((unsigned)f2bf(accH[2] * inv) << 16) | f2bf(accL[2] * inv);
                o.w = ((unsigned)f2bf(accH[3] * inv) << 16) | f2bf(accL[3] * inv);
                // row ld (256 B stride), chunk c, XOR-swizzled per row
                const int byte = (c * 16) ^ ((ld & 7) << 4);
                *(uint4*)((char*)agg + ld * 256 + byte) = o;
            }
            __syncthreads();

            // MFMA pass: K-quarter q = kb q*4 .. q*4+3, rows of half h
            #pragma unroll
            for (int kbl = 0; kbl < 4; ++kbl) {
                short8 a[2];
                #pragma unroll
                for (int rt = 0; rt < 2; ++rt) {
                    const int row  = rt * 16 + lrow;
                    const int byte = (kbl * 64 + quad * 16) ^ ((row & 7) << 4);
                    a[rt] = *(const short8*)((const char*)agg + row * 256 + byte);
                }
                const int kb = q * 4 + kbl;
                const unsigned short* wp = Wsw + ((size_t)(kb * 8 + ct0) * 64 + l) * 8;
                const short8 b0 = *(const short8*)wp;
                const short8 b1 = *(const short8*)(wp + 64 * 8);
                acc[0][0] = __builtin_amdgcn_mfma_f32_16x16x32_bf16(a[0], b0, acc[0][0], 0, 0, 0);
                acc[1][0] = __builtin_amdgcn_mfma_f32_16x16x32_bf16(a[1], b0, acc[1][0], 0, 0, 0);
                acc[0][1] = __builtin_amdgcn_mfma_f32_16x16x32_bf16(a[0], b1, acc[0][1], 0, 0, 0);
                acc[1][1] = __builtin_amdgcn_mfma_f32_16x16x32_bf16(a[1], b1, acc[1][1], 0, 0, 0);
            }
        }

        // ---- epilogue for half h: bias + ReLU + store ----
        #pragma unroll
        for (int ci = 0; ci < 2; ++ci) {
            const int col = (ct0 + ci) * 16 + lrow;
            const float bv = bsum[col];
            #pragma unroll
            for (int rt = 0; rt < 2; ++rt) {
                #pragma unroll
                for (int e = 0; e < 4; ++e) {
                    const int row = dst0 + h * 32 + rt * 16 + quad * 4 + e;
                    if (row < N)
                        out[(size_t)row * D + col] = fmaxf(acc[rt][ci][e] + bv, 0.f);
                }
            }
        }
    }
    #undef ACCUM
}

static inline size_t align_up(size_t v, size_t a) { return (v + a - 1) & ~(a - 1); }

extern "C" void kernel_launch(void* const* d_in, const int* in_sizes, int n_in,
                              void* d_out, int out_size, void* d_ws, size_t ws_size,
                              hipStream_t stream)
{
    const float* x    = (const float*)d_in[0];   // [N, 128]
    const float* W    = (const float*)d_in[1];   // [4, 128, 128]
    const float* bias = (const float*)d_in[2];   // [4, 128]
    const int* src    = (const int*)d_in[3];     // [4, E]
    const int* dst    = (const int*)d_in[4];     // [4, E]
    float* out        = (float*)d_out;           // [N, 128]

    const int N = in_sizes[0] / D;               // 100000
    const int E = in_sizes[3] / NREL;            // 500000
    const int nG = NREL * N;                     // 400000 buckets
    const int totalE = NREL * E;                 // 2000000 edges
    const int nbins  = (nG + NBK - 1) >> BINSHIFT;  // 1563

    char* w = (char*)d_ws;
    int* binCnt = (int*)w;            w += align_up((size_t)nbins * SUBW * BPAD * 4, 256);
    unsigned int* part = (unsigned int*)w;     w += align_up((size_t)nbins * WCAP * 4, 256);
    unsigned short* Wsw = (unsigned short*)w;  w += align_up((size_t)512 * D * 2, 256);
    float* bsum = (float*)w;          w += align_up((size_t)D * 4, 256);
    unsigned short* xB = (unsigned short*)w;   // [N][128] bf16

    const int p1_blocks = 2048;

    hipMemsetAsync(binCnt, 0, (size_t)nbins * SUBW * BPAD * sizeof(int), stream);
    part1prep_kernel<<<p1_blocks, 256, 0, stream>>>(
        x, W, bias, src, dst, binCnt, part, xB, Wsw, bsum, E, N, nbins, totalE);
    agg_gemm_kernel<<<nbins, 256, 0, stream>>>(part, binCnt, xB, Wsw, bsum, out, N);
}

// Round 8
// 283.575 us; speedup vs baseline: 1.7194x; 1.0031x over previous
//
#include <hip/hip_runtime.h>

#define D 128          // D_IN == D_OUT == 128
#define NREL 4
#define BINSHIFT 8     // 256 buckets per coarse bin
#define NBK 256        // buckets per bin
#define BCAP 1664      // edge capacity per bin window (mean 1280, +10.7 sigma)
#define BPAD 32        // ints per counter slot (128 B = 1 L2 line; r5/r6 showed
                       // same-line atomics serialize ~225 cy)
#define NSCAT 128      // scatter blocks. Global atomics = NSCAT*nbins ~= 200K.
                       // r7 measured global-atomic THROUGHPUT ~8 ops/cy device-
                       // wide (2M atomics = 103 us); batched reserve cuts count
                       // 10x -> ~10 us. Chains 128*225cy ~= 12 us, parallel.
#define NBINS_MAX 1600

typedef __attribute__((ext_vector_type(8))) short short8;
typedef __attribute__((ext_vector_type(4))) float f32x4;

static __device__ inline unsigned short f2bf(float f) {
    unsigned int u = __float_as_uint(f);
    u += 0x7fffu + ((u >> 16) & 1u);   // round-to-nearest-even
    return (unsigned short)(u >> 16);
}

// ---------------------------------------------------------------------------
// part1 + prep, two-pass batched scatter. Bucket key DST-MAJOR: g = dst*4+rel,
// one bin (256 buckets) = 64 dsts x 4 rels = one M=64, K=512 output tile.
//  A) blocks 0..NSCAT-1, chunk = total/NSCAT edges each:
//     pass1: LDS histogram (1563 bins, LDS atomics only);
//     reserve: ONE global atomicAdd per non-empty bin -> absolute base;
//     pass2: re-read chunk (L2-hot), place via LDS cursor++, scattered store.
//     No edge storage in LDS (6.4 KB total) -> occupancy unconstrained.
//  B) all blocks: grid-stride xcast (f32->bf16), W swizzle, bias sum.
// Entry = src | (g&255)<<17, bin = g>>8.
// ---------------------------------------------------------------------------
__global__ __launch_bounds__(256) void part1prep_kernel(
    const float* __restrict__ x,      // [N][128]
    const float* __restrict__ W,      // [4][128][128]
    const float* __restrict__ bias,   // [4][128]
    const int* __restrict__ src, const int* __restrict__ dst,
    int* __restrict__ binCnt, unsigned int* __restrict__ part,
    unsigned short* __restrict__ xB,  // [N][128] bf16
    unsigned short* __restrict__ Wsw, // [16][8][64][8] bf16
    float* __restrict__ bsum,         // [128]
    int E, int N, int nbins, int total)
{
    __shared__ int hist[NBINS_MAX];   // 6.4 KB: count -> absolute cursor

    const int t     = threadIdx.x;
    const int gtid  = blockIdx.x * 256 + t;
    const int gsize = gridDim.x * 256;
    const int E2 = 2 * E, E3 = 3 * E;

    // ================= Phase A: batched scatter (blocks < NSCAT) ===========
    if (blockIdx.x < NSCAT) {
        const int chunk = (total + NSCAT - 1) / NSCAT;
        const int e0 = blockIdx.x * chunk;
        const int n  = min(chunk, total - e0);

        for (int i = t; i < nbins; i += 256) hist[i] = 0;
        __syncthreads();

        // pass 1: count
        for (int i = t; i < n; i += 256) {
            const int e = e0 + i;
            const int g = (dst[e] << 2) | ((e >= E) + (e >= E2) + (e >= E3));
            atomicAdd(&hist[g >> BINSHIFT], 1);
        }
        __syncthreads();

        // reserve: one global atomic per non-empty bin; hist becomes ABSOLUTE cursor
        for (int b = t; b < nbins; b += 256) {
            const int h = hist[b];
            hist[b] = h ? b * BCAP + atomicAdd(&binCnt[b * BPAD], h) : 0;
        }
        __syncthreads();

        // pass 2: place (chunk re-read is L2-hot)
        for (int i = t; i < n; i += 256) {
            const int e = e0 + i;
            const int g = (dst[e] << 2) | ((e >= E) + (e >= E2) + (e >= E3));
            const int bin = g >> BINSHIFT;
            const unsigned entry = (unsigned)src[e] | ((unsigned)(g & (NBK - 1)) << 17);
            const int pos = atomicAdd(&hist[bin], 1);        // LDS cursor
            if (pos < (bin + 1) * BCAP)                      // 10.7-sigma guard
                part[pos] = entry;
        }
    }

    // ================= Phase B: prep (all blocks, grid-stride) ==============
    if (gtid < D)
        bsum[gtid] = bias[gtid] + bias[D + gtid] + bias[2 * D + gtid] + bias[3 * D + gtid];

    for (int gid = gtid; gid < 8192; gid += gsize) {
        const int l   = gid & 63;
        const int ct  = (gid >> 6) & 7;
        const int kb  = gid >> 9;
        const int rel = kb >> 2;
        const int kbase = (kb & 3) * 32 + (l >> 4) * 8;
        const int nn = ct * 16 + (l & 15);
        ushort4 v0, v1;
        const float* wp = W + (size_t)rel * D * D + (size_t)kbase * D + nn;
        v0.x = f2bf(wp[0 * D]); v0.y = f2bf(wp[1 * D]);
        v0.z = f2bf(wp[2 * D]); v0.w = f2bf(wp[3 * D]);
        v1.x = f2bf(wp[4 * D]); v1.y = f2bf(wp[5 * D]);
        v1.z = f2bf(wp[6 * D]); v1.w = f2bf(wp[7 * D]);
        ushort4* op = (ushort4*)(Wsw + (size_t)gid * 8);
        op[0] = v0;
        op[1] = v1;
    }

    const int n4 = N * D / 4;
    for (int i = gtid; i < n4; i += gsize) {
        const float4 v = ((const float4*)x)[i];
        ushort4 o;
        o.x = f2bf(v.x); o.y = f2bf(v.y); o.z = f2bf(v.z); o.w = f2bf(v.w);
        ((ushort4*)xB)[i] = o;
    }
}

// ---------------------------------------------------------------------------
// Fused aggregate + GEMM + bias + ReLU. ONE block per bin (M=64 dsts).
//  A) read part[] ONCE: histogram + raw staging into the idle agg region
//     (8 KB >= 6.7 KB); scan; LDS counting-sort into sh_s.
//  B/C) 2 half-tiles (M=32) x 4 rel-quarters: gather rel q of half h ->
//     bf16 LDS tile agg[32][128] (XOR-swizzled), sync, 4-kb MFMA pass into
//     per-half VGPR acc[2][2], sync; per-half epilogue (bias+ReLU+store).
// LDS 18.4 KB -> 8 blocks/CU (wave-limit cap). Edge list stays in LDS.
// ---------------------------------------------------------------------------
__global__ __launch_bounds__(256, 8) void agg_gemm_kernel(
    const unsigned int* __restrict__ part,
    const int* __restrict__ binCnt,
    const unsigned short* __restrict__ xB,   // [N][128] bf16
    const unsigned short* __restrict__ Wsw,  // [16][8][64][8] bf16
    const float* __restrict__ bsum,          // [128]
    float* __restrict__ out,                 // [N][128]
    int N)
{
    __shared__ int sh_s[BCAP];                         // 6.7 KB sorted src
    __shared__ int hist[NBK];                          // 1 KB
    __shared__ int scanbuf[NBK];                       // 1 KB
    __shared__ int offl[NBK + 1];                      // 1 KB
    __shared__ __align__(16) unsigned short agg[32 * 128];  // 8 KB, swizzled
    // phase-A overlay: raw entry staging in the idle agg region (6.7 <= 8 KB)
    unsigned int* raw = (unsigned int*)agg;

    const int t    = threadIdx.x;
    const int b    = blockIdx.x;
    const size_t base = (size_t)b * BCAP;
    const int cnt  = min(binCnt[b * BPAD], BCAP);
    const int dst0 = b * 64;

    // ---- A: histogram + raw staging (single part[] read) ----
    hist[t] = 0;
    __syncthreads();
    for (int i = t; i < cnt; i += 256) {
        const unsigned v = part[base + i];
        raw[i] = v;
        atomicAdd(&hist[v >> 17], 1);
    }
    __syncthreads();

    const int myc = hist[t];
    scanbuf[t] = myc;
    __syncthreads();
    for (int off = 1; off < 256; off <<= 1) {
        int v = (t >= off) ? scanbuf[t - off] : 0;
        __syncthreads();
        scanbuf[t] += v;
        __syncthreads();
    }
    offl[t] = scanbuf[t] - myc;
    if (t == 255) offl[256] = scanbuf[255];
    hist[t] = scanbuf[t] - myc;           // cursor
    __syncthreads();

    // sort: LDS raw -> LDS sh_s
    for (int i = t; i < cnt; i += 256) {
        const unsigned v = raw[i];
        const int pos = atomicAdd(&hist[v >> 17], 1);
        sh_s[pos] = (int)(v & 0x1FFFF);
    }
    __syncthreads();

    // ---- B/C: 2 halves x 4 rel-quarters of gather -> LDS -> MFMA ----
    const int c    = t & 15;        // 16-byte chunk index (8 bf16)
    const int team = t >> 4;        // unit slot 0..15

    const int wv   = t >> 6;
    const int l    = t & 63;
    const int lrow = l & 15;
    const int quad = l >> 4;
    const int ct0  = wv * 2;        // each wave: 2 col-tiles x 2 row-tiles

    #define ACCUM(v)                                        \
        accL[0] += __uint_as_float((v).x << 16);            \
        accH[0] += __uint_as_float((v).x & 0xffff0000u);    \
        accL[1] += __uint_as_float((v).y << 16);            \
        accH[1] += __uint_as_float((v).y & 0xffff0000u);    \
        accL[2] += __uint_as_float((v).z << 16);            \
        accH[2] += __uint_as_float((v).z & 0xffff0000u);    \
        accL[3] += __uint_as_float((v).w << 16);            \
        accH[3] += __uint_as_float((v).w & 0xffff0000u);

    #pragma unroll 1
    for (int h = 0; h < 2; ++h) {
        f32x4 acc[2][2] = {};

        #pragma unroll 1
        for (int q = 0; q < NREL; ++q) {
            if (h | q) __syncthreads();   // previous MFMA pass done with agg

            // gather: 32 buckets of half h, rel q (bucket = (h*32+ld)*4+q)
            for (int ld = team; ld < 32; ld += 16) {
                const int bkt = (h * 32 + ld) * 4 + q;
                const int beg = offl[bkt];
                const int end = offl[bkt + 1];
                const float inv = 1.0f / fmaxf((float)(end - beg), 1.0f);

                float accL[4] = {0.f, 0.f, 0.f, 0.f};
                float accH[4] = {0.f, 0.f, 0.f, 0.f};

                int j = beg;
                for (; j + 3 < end; j += 4) {
                    const int s0 = sh_s[j];
                    const int s1 = sh_s[j + 1];
                    const int s2 = sh_s[j + 2];
                    const int s3 = sh_s[j + 3];
                    const uint4 v0 = *(const uint4*)(xB + (size_t)s0 * D + c * 8);
                    const uint4 v1 = *(const uint4*)(xB + (size_t)s1 * D + c * 8);
                    const uint4 v2 = *(const uint4*)(xB + (size_t)s2 * D + c * 8);
                    const uint4 v3 = *(const uint4*)(xB + (size_t)s3 * D + c * 8);
                    ACCUM(v0) ACCUM(v1) ACCUM(v2) ACCUM(v3)
                }
                for (; j < end; ++j) {
                    const uint4 v0 = *(const uint4*)(xB + (size_t)sh_s[j] * D + c * 8);
                    ACCUM(v0)
                }

                uint4 o;
                o.x = ((unsigned)f2bf(accH[0] * inv) << 16) | f2bf(accL[0] * inv);
                o.y = ((unsigned)f2bf(accH[1] * inv) << 16) | f2bf(accL[1] * inv);
                o.z = ((unsigned)f2bf(accH[2] * inv) << 16) | f2bf(accL[2] * inv);
                o.w = ((unsigned)f2bf(accH[3] * inv) << 16) | f2bf(accL[3] * inv);
                // row ld (256 B stride), chunk c, XOR-swizzled per row
                const int byte = (c * 16) ^ ((ld & 7) << 4);
                *(uint4*)((char*)agg + ld * 256 + byte) = o;
            }
            __syncthreads();

            // MFMA pass: K-quarter q = kb q*4 .. q*4+3, rows of half h
            #pragma unroll
            for (int kbl = 0; kbl < 4; ++kbl) {
                short8 a[2];
                #pragma unroll
                for (int rt = 0; rt < 2; ++rt) {
                    const int row  = rt * 16 + lrow;
                    const int byte = (kbl * 64 + quad * 16) ^ ((row & 7) << 4);
                    a[rt] = *(const short8*)((const char*)agg + row * 256 + byte);
                }
                const int kb = q * 4 + kbl;
                const unsigned short* wp = Wsw + ((size_t)(kb * 8 + ct0) * 64 + l) * 8;
                const short8 b0 = *(const short8*)wp;
                const short8 b1 = *(const short8*)(wp + 64 * 8);
                acc[0][0] = __builtin_amdgcn_mfma_f32_16x16x32_bf16(a[0], b0, acc[0][0], 0, 0, 0);
                acc[1][0] = __builtin_amdgcn_mfma_f32_16x16x32_bf16(a[1], b0, acc[1][0], 0, 0, 0);
                acc[0][1] = __builtin_amdgcn_mfma_f32_16x16x32_bf16(a[0], b1, acc[0][1], 0, 0, 0);
                acc[1][1] = __builtin_amdgcn_mfma_f32_16x16x32_bf16(a[1], b1, acc[1][1], 0, 0, 0);
            }
        }

        // ---- epilogue for half h: bias + ReLU + store ----
        #pragma unroll
        for (int ci = 0; ci < 2; ++ci) {
            const int col = (ct0 + ci) * 16 + lrow;
            const float bv = bsum[col];
            #pragma unroll
            for (int rt = 0; rt < 2; ++rt) {
                #pragma unroll
                for (int e = 0; e < 4; ++e) {
                    const int row = dst0 + h * 32 + rt * 16 + quad * 4 + e;
                    if (row < N)
                        out[(size_t)row * D + col] = fmaxf(acc[rt][ci][e] + bv, 0.f);
                }
            }
        }
    }
    #undef ACCUM
}

static inline size_t align_up(size_t v, size_t a) { return (v + a - 1) & ~(a - 1); }

extern "C" void kernel_launch(void* const* d_in, const int* in_sizes, int n_in,
                              void* d_out, int out_size, void* d_ws, size_t ws_size,
                              hipStream_t stream)
{
    const float* x    = (const float*)d_in[0];   // [N, 128]
    const float* W    = (const float*)d_in[1];   // [4, 128, 128]
    const float* bias = (const float*)d_in[2];   // [4, 128]
    const int* src    = (const int*)d_in[3];     // [4, E]
    const int* dst    = (const int*)d_in[4];     // [4, E]
    float* out        = (float*)d_out;           // [N, 128]

    const int N = in_sizes[0] / D;               // 100000
    const int E = in_sizes[3] / NREL;            // 500000
    const int nG = NREL * N;                     // 400000 buckets
    const int totalE = NREL * E;                 // 2000000 edges
    const int nbins  = (nG + NBK - 1) >> BINSHIFT;  // 1563

    char* w = (char*)d_ws;
    int* binCnt = (int*)w;            w += align_up((size_t)nbins * BPAD * 4, 256);
    unsigned int* part = (unsigned int*)w;     w += align_up((size_t)nbins * BCAP * 4, 256);
    unsigned short* Wsw = (unsigned short*)w;  w += align_up((size_t)512 * D * 2, 256);
    float* bsum = (float*)w;          w += align_up((size_t)D * 4, 256);
    unsigned short* xB = (unsigned short*)w;   // [N][128] bf16

    const int p1_blocks = 2048;

    hipMemsetAsync(binCnt, 0, (size_t)nbins * BPAD * sizeof(int), stream);
    part1prep_kernel<<<p1_blocks, 256, 0, stream>>>(
        x, W, bias, src, dst, binCnt, part, xB, Wsw, bsum, E, N, nbins, totalE);
    agg_gemm_kernel<<<nbins, 256, 0, stream>>>(part, binCnt, xB, Wsw, bsum, out, N);
}

// Round 9
// 240.026 us; speedup vs baseline: 2.0313x; 1.1814x over previous
//
#include <hip/hip_runtime.h>

#define D 128          // D_IN == D_OUT == 128
#define NREL 4
#define BINSHIFT 8     // 256 buckets per coarse bin
#define NBK 256        // buckets per bin
#define BCAP 1664      // edge capacity per bin window (mean 1280, +10.7 sigma)
#define BPAD 32        // ints per counter slot (128 B = 1 L2 line; r5/r6: same-
                       // line atomics serialize ~225 cy EACH, latency not tput)
#define NSCAT 256      // scatter blocks (1024 thr = 16 waves each -> 16 waves/CU
                       // in phase A; r8's 128x4-wave blocks = 2 waves/CU was the
                       // stall). Reserve chains: NSCAT*225cy ~= 24 us, overlapped.
#define KPT 8          // edges/thread, register-carried between passes
#define NBINS_MAX 1600

typedef __attribute__((ext_vector_type(8))) short short8;
typedef __attribute__((ext_vector_type(4))) float f32x4;

static __device__ inline unsigned short f2bf(float f) {
    unsigned int u = __float_as_uint(f);
    u += 0x7fffu + ((u >> 16) & 1u);   // round-to-nearest-even
    return (unsigned short)(u >> 16);
}

// ---------------------------------------------------------------------------
// part1 + prep, two-pass batched scatter, 1024-thread blocks.
// Bucket key DST-MAJOR: g = dst*4+rel; one bin = 64 dsts x 4 rels.
//  A) blocks 0..NSCAT-1, chunk = ceil(total/NSCAT) edges:
//     pass1: read src/dst ONCE, keep (entry,bin) in registers (KPT=8/thread),
//            LDS histogram (1563 bins, LDS atomics);
//     reserve: ONE global atomicAdd per non-empty bin -> absolute cursor;
//     pass2: place from registers via LDS cursor++, scattered store.
//  B) all blocks: grid-stride xcast (f32->bf16), W swizzle, bias sum.
// Entry = src | (g&255)<<17, bin = g>>8. LDS 6.4 KB.
// ---------------------------------------------------------------------------
__global__ __launch_bounds__(1024) void part1prep_kernel(
    const float* __restrict__ x,      // [N][128]
    const float* __restrict__ W,      // [4][128][128]
    const float* __restrict__ bias,   // [4][128]
    const int* __restrict__ src, const int* __restrict__ dst,
    int* __restrict__ binCnt, unsigned int* __restrict__ part,
    unsigned short* __restrict__ xB,  // [N][128] bf16
    unsigned short* __restrict__ Wsw, // [16][8][64][8] bf16
    float* __restrict__ bsum,         // [128]
    int E, int N, int nbins, int total)
{
    __shared__ int hist[NBINS_MAX];   // 6.4 KB: count -> absolute cursor

    const int t     = threadIdx.x;
    const int gtid  = blockIdx.x * 1024 + t;
    const int gsize = gridDim.x * 1024;
    const int E2 = 2 * E, E3 = 3 * E;

    // ================= Phase A: batched scatter (blocks < NSCAT) ===========
    if (blockIdx.x < NSCAT) {
        const int chunk = (total + NSCAT - 1) / NSCAT;   // 7813
        const int e0 = blockIdx.x * chunk;
        const int n  = min(chunk, total - e0);

        for (int i = t; i < nbins; i += 1024) hist[i] = 0;
        __syncthreads();

        // pass 1: read once, decode, register-carry, count
        unsigned ebuf[KPT];
        int      bbuf[KPT];
        #pragma unroll
        for (int k = 0; k < KPT; ++k) {
            const int i = t + k * 1024;
            bbuf[k] = -1;
            if (i < n) {
                const int e = e0 + i;
                const int g = (dst[e] << 2) | ((e >= E) + (e >= E2) + (e >= E3));
                ebuf[k] = (unsigned)src[e] | ((unsigned)(g & (NBK - 1)) << 17);
                bbuf[k] = g >> BINSHIFT;
                atomicAdd(&hist[bbuf[k]], 1);
            }
        }
        __syncthreads();

        // reserve: one global atomic per non-empty bin -> ABSOLUTE cursor
        for (int b = t; b < nbins; b += 1024) {
            const int h = hist[b];
            hist[b] = h ? b * BCAP + atomicAdd(&binCnt[b * BPAD], h) : 0;
        }
        __syncthreads();

        // pass 2: place from registers
        #pragma unroll
        for (int k = 0; k < KPT; ++k) {
            if (bbuf[k] >= 0) {
                const int pos = atomicAdd(&hist[bbuf[k]], 1);    // LDS cursor
                if (pos < (bbuf[k] + 1) * BCAP)                  // 10.7-sigma guard
                    part[pos] = ebuf[k];
            }
        }
    }

    // ================= Phase B: prep (all blocks, grid-stride) ==============
    if (gtid < D)
        bsum[gtid] = bias[gtid] + bias[D + gtid] + bias[2 * D + gtid] + bias[3 * D + gtid];

    for (int gid = gtid; gid < 8192; gid += gsize) {
        const int l   = gid & 63;
        const int ct  = (gid >> 6) & 7;
        const int kb  = gid >> 9;
        const int rel = kb >> 2;
        const int kbase = (kb & 3) * 32 + (l >> 4) * 8;
        const int nn = ct * 16 + (l & 15);
        ushort4 v0, v1;
        const float* wp = W + (size_t)rel * D * D + (size_t)kbase * D + nn;
        v0.x = f2bf(wp[0 * D]); v0.y = f2bf(wp[1 * D]);
        v0.z = f2bf(wp[2 * D]); v0.w = f2bf(wp[3 * D]);
        v1.x = f2bf(wp[4 * D]); v1.y = f2bf(wp[5 * D]);
        v1.z = f2bf(wp[6 * D]); v1.w = f2bf(wp[7 * D]);
        ushort4* op = (ushort4*)(Wsw + (size_t)gid * 8);
        op[0] = v0;
        op[1] = v1;
    }

    const int n4 = N * D / 4;
    for (int i = gtid; i < n4; i += gsize) {
        const float4 v = ((const float4*)x)[i];
        ushort4 o;
        o.x = f2bf(v.x); o.y = f2bf(v.y); o.z = f2bf(v.z); o.w = f2bf(v.w);
        ((ushort4*)xB)[i] = o;
    }
}

// ---------------------------------------------------------------------------
// Fused aggregate + GEMM + bias + ReLU. ONE block per bin (M=64 dsts).
//  A) read part[] ONCE: histogram + raw staging into the idle agg region
//     (8 KB >= 6.7 KB); scan; LDS counting-sort into sh_s.
//  B/C) 2 half-tiles (M=32) x 4 rel-quarters: gather rel q of half h ->
//     bf16 LDS tile agg[32][128] (XOR-swizzled), sync, 4-kb MFMA pass into
//     per-half VGPR acc[2][2], sync; per-half epilogue (bias+ReLU+store).
// LDS 18.4 KB -> 8 blocks/CU (wave-limit cap). Edge list stays in LDS.
// ---------------------------------------------------------------------------
__global__ __launch_bounds__(256, 8) void agg_gemm_kernel(
    const unsigned int* __restrict__ part,
    const int* __restrict__ binCnt,
    const unsigned short* __restrict__ xB,   // [N][128] bf16
    const unsigned short* __restrict__ Wsw,  // [16][8][64][8] bf16
    const float* __restrict__ bsum,          // [128]
    float* __restrict__ out,                 // [N][128]
    int N)
{
    __shared__ int sh_s[BCAP];                         // 6.7 KB sorted src
    __shared__ int hist[NBK];                          // 1 KB
    __shared__ int scanbuf[NBK];                       // 1 KB
    __shared__ int offl[NBK + 1];                      // 1 KB
    __shared__ __align__(16) unsigned short agg[32 * 128];  // 8 KB, swizzled
    // phase-A overlay: raw entry staging in the idle agg region (6.7 <= 8 KB)
    unsigned int* raw = (unsigned int*)agg;

    const int t    = threadIdx.x;
    const int b    = blockIdx.x;
    const size_t base = (size_t)b * BCAP;
    const int cnt  = min(binCnt[b * BPAD], BCAP);
    const int dst0 = b * 64;

    // ---- A: histogram + raw staging (single part[] read) ----
    hist[t] = 0;
    __syncthreads();
    for (int i = t; i < cnt; i += 256) {
        const unsigned v = part[base + i];
        raw[i] = v;
        atomicAdd(&hist[v >> 17], 1);
    }
    __syncthreads();

    const int myc = hist[t];
    scanbuf[t] = myc;
    __syncthreads();
    for (int off = 1; off < 256; off <<= 1) {
        int v = (t >= off) ? scanbuf[t - off] : 0;
        __syncthreads();
        scanbuf[t] += v;
        __syncthreads();
    }
    offl[t] = scanbuf[t] - myc;
    if (t == 255) offl[256] = scanbuf[255];
    hist[t] = scanbuf[t] - myc;           // cursor
    __syncthreads();

    // sort: LDS raw -> LDS sh_s
    for (int i = t; i < cnt; i += 256) {
        const unsigned v = raw[i];
        const int pos = atomicAdd(&hist[v >> 17], 1);
        sh_s[pos] = (int)(v & 0x1FFFF);
    }
    __syncthreads();

    // ---- B/C: 2 halves x 4 rel-quarters of gather -> LDS -> MFMA ----
    const int c    = t & 15;        // 16-byte chunk index (8 bf16)
    const int team = t >> 4;        // unit slot 0..15

    const int wv   = t >> 6;
    const int l    = t & 63;
    const int lrow = l & 15;
    const int quad = l >> 4;
    const int ct0  = wv * 2;        // each wave: 2 col-tiles x 2 row-tiles

    #define ACCUM(v)                                        \
        accL[0] += __uint_as_float((v).x << 16);            \
        accH[0] += __uint_as_float((v).x & 0xffff0000u);    \
        accL[1] += __uint_as_float((v).y << 16);            \
        accH[1] += __uint_as_float((v).y & 0xffff0000u);    \
        accL[2] += __uint_as_float((v).z << 16);            \
        accH[2] += __uint_as_float((v).z & 0xffff0000u);    \
        accL[3] += __uint_as_float((v).w << 16);            \
        accH[3] += __uint_as_float((v).w & 0xffff0000u);

    #pragma unroll 1
    for (int h = 0; h < 2; ++h) {
        f32x4 acc[2][2] = {};

        #pragma unroll 1
        for (int q = 0; q < NREL; ++q) {
            if (h | q) __syncthreads();   // previous MFMA pass done with agg

            // gather: 32 buckets of half h, rel q (bucket = (h*32+ld)*4+q)
            for (int ld = team; ld < 32; ld += 16) {
                const int bkt = (h * 32 + ld) * 4 + q;
                const int beg = offl[bkt];
                const int end = offl[bkt + 1];
                const float inv = 1.0f / fmaxf((float)(end - beg), 1.0f);

                float accL[4] = {0.f, 0.f, 0.f, 0.f};
                float accH[4] = {0.f, 0.f, 0.f, 0.f};

                int j = beg;
                for (; j + 3 < end; j += 4) {
                    const int s0 = sh_s[j];
                    const int s1 = sh_s[j + 1];
                    const int s2 = sh_s[j + 2];
                    const int s3 = sh_s[j + 3];
                    const uint4 v0 = *(const uint4*)(xB + (size_t)s0 * D + c * 8);
                    const uint4 v1 = *(const uint4*)(xB + (size_t)s1 * D + c * 8);
                    const uint4 v2 = *(const uint4*)(xB + (size_t)s2 * D + c * 8);
                    const uint4 v3 = *(const uint4*)(xB + (size_t)s3 * D + c * 8);
                    ACCUM(v0) ACCUM(v1) ACCUM(v2) ACCUM(v3)
                }
                for (; j < end; ++j) {
                    const uint4 v0 = *(const uint4*)(xB + (size_t)sh_s[j] * D + c * 8);
                    ACCUM(v0)
                }

                uint4 o;
                o.x = ((unsigned)f2bf(accH[0] * inv) << 16) | f2bf(accL[0] * inv);
                o.y = ((unsigned)f2bf(accH[1] * inv) << 16) | f2bf(accL[1] * inv);
                o.z = ((unsigned)f2bf(accH[2] * inv) << 16) | f2bf(accL[2] * inv);
                o.w = ((unsigned)f2bf(accH[3] * inv) << 16) | f2bf(accL[3] * inv);
                // row ld (256 B stride), chunk c, XOR-swizzled per row
                const int byte = (c * 16) ^ ((ld & 7) << 4);
                *(uint4*)((char*)agg + ld * 256 + byte) = o;
            }
            __syncthreads();

            // MFMA pass: K-quarter q = kb q*4 .. q*4+3, rows of half h
            #pragma unroll
            for (int kbl = 0; kbl < 4; ++kbl) {
                short8 a[2];
                #pragma unroll
                for (int rt = 0; rt < 2; ++rt) {
                    const int row  = rt * 16 + lrow;
                    const int byte = (kbl * 64 + quad * 16) ^ ((row & 7) << 4);
                    a[rt] = *(const short8*)((const char*)agg + row * 256 + byte);
                }
                const int kb = q * 4 + kbl;
                const unsigned short* wp = Wsw + ((size_t)(kb * 8 + ct0) * 64 + l) * 8;
                const short8 b0 = *(const short8*)wp;
                const short8 b1 = *(const short8*)(wp + 64 * 8);
                acc[0][0] = __builtin_amdgcn_mfma_f32_16x16x32_bf16(a[0], b0, acc[0][0], 0, 0, 0);
                acc[1][0] = __builtin_amdgcn_mfma_f32_16x16x32_bf16(a[1], b0, acc[1][0], 0, 0, 0);
                acc[0][1] = __builtin_amdgcn_mfma_f32_16x16x32_bf16(a[0], b1, acc[0][1], 0, 0, 0);
                acc[1][1] = __builtin_amdgcn_mfma_f32_16x16x32_bf16(a[1], b1, acc[1][1], 0, 0, 0);
            }
        }

        // ---- epilogue for half h: bias + ReLU + store ----
        #pragma unroll
        for (int ci = 0; ci < 2; ++ci) {
            const int col = (ct0 + ci) * 16 + lrow;
            const float bv = bsum[col];
            #pragma unroll
            for (int rt = 0; rt < 2; ++rt) {
                #pragma unroll
                for (int e = 0; e < 4; ++e) {
                    const int row = dst0 + h * 32 + rt * 16 + quad * 4 + e;
                    if (row < N)
                        out[(size_t)row * D + col] = fmaxf(acc[rt][ci][e] + bv, 0.f);
                }
            }
        }
    }
    #undef ACCUM
}

static inline size_t align_up(size_t v, size_t a) { return (v + a - 1) & ~(a - 1); }

extern "C" void kernel_launch(void* const* d_in, const int* in_sizes, int n_in,
                              void* d_out, int out_size, void* d_ws, size_t ws_size,
                              hipStream_t stream)
{
    const float* x    = (const float*)d_in[0];   // [N, 128]
    const float* W    = (const float*)d_in[1];   // [4, 128, 128]
    const float* bias = (const float*)d_in[2];   // [4, 128]
    const int* src    = (const int*)d_in[3];     // [4, E]
    const int* dst    = (const int*)d_in[4];     // [4, E]
    float* out        = (float*)d_out;           // [N, 128]

    const int N = in_sizes[0] / D;               // 100000
    const int E = in_sizes[3] / NREL;            // 500000
    const int nG = NREL * N;                     // 400000 buckets
    const int totalE = NREL * E;                 // 2000000 edges
    const int nbins  = (nG + NBK - 1) >> BINSHIFT;  // 1563

    char* w = (char*)d_ws;
    int* binCnt = (int*)w;            w += align_up((size_t)nbins * BPAD * 4, 256);
    unsigned int* part = (unsigned int*)w;     w += align_up((size_t)nbins * BCAP * 4, 256);
    unsigned short* Wsw = (unsigned short*)w;  w += align_up((size_t)512 * D * 2, 256);
    float* bsum = (float*)w;          w += align_up((size_t)D * 4, 256);
    unsigned short* xB = (unsigned short*)w;   // [N][128] bf16

    const int p1_blocks = 512;                   // 512 x 1024 thr = 32 waves/CU

    hipMemsetAsync(binCnt, 0, (size_t)nbins * BPAD * sizeof(int), stream);
    part1prep_kernel<<<p1_blocks, 1024, 0, stream>>>(
        x, W, bias, src, dst, binCnt, part, xB, Wsw, bsum, E, N, nbins, totalE);
    agg_gemm_kernel<<<nbins, 256, 0, stream>>>(part, binCnt, xB, Wsw, bsum, out, N);
}